// Round 1
// baseline (382.982 us; speedup 1.0000x reference)
//
#include <hip/hip_runtime.h>
#include <stdint.h>

namespace {
constexpr int B = 128;
constexpr int N = 4096;
constexpr int S = 32;
constexpr int P = 64;
constexpr int D = 128;
constexpr int K = 384;          // 3*D
constexpr int ROWS = 8;         // rows per block in pm_emb kernel
}

// ---- bf16 pack/unpack helpers (RNE pack) ----
__device__ __forceinline__ uint32_t f2bf(float f) {
    union { float f; uint32_t u; } v; v.f = f;
    return (v.u + 0x7FFFu + ((v.u >> 16) & 1u)) >> 16;
}
__device__ __forceinline__ uint32_t pack2(float x, float y) {
    return f2bf(x) | (f2bf(y) << 16);
}
__device__ __forceinline__ float blo(uint32_t u) {
    union { uint32_t u; float f; } t; t.u = u << 16; return t.f;
}
__device__ __forceinline__ float bhi(uint32_t u) {
    union { uint32_t u; float f; } t; t.u = u & 0xFFFF0000u; return t.f;
}

// Kernel 1: pm_emb = concat([stage, wafer, dyn]) @ W_concat  -> out rows 0..P-1
// One wave (64 threads) per block; each lane owns columns d=lane and d+64.
// 8 rows per block; activations packed bf16 in LDS (one ds_read_b128 = 8 k).
__global__ __launch_bounds__(64) void pm_emb_kernel(
    const float* __restrict__ enc_row,   // [B,N,D]
    const float* __restrict__ enc_col,   // [B,S,D]
    const float* __restrict__ clockp,    // [B]
    const float* __restrict__ lpet,      // [B,P]
    const float* __restrict__ W_dyn,     // [2,D]
    const float* __restrict__ W_concat,  // [K,D]
    const int*   __restrict__ lhw,       // [B,P]
    const int*   __restrict__ lstage,    // [B,P]
    float* __restrict__ out)             // [B,P+2,D]
{
    __shared__ uint32_t xs[ROWS][K / 2];   // bf16 pairs, k-major per row
    const int lane = threadIdx.x;          // 0..63
    const int r0 = blockIdx.x * ROWS;      // rid = b*P + p

    // Phase 1: gather + build x rows (bf16-packed). Lane handles d=2*lane, 2*lane+1.
    #pragma unroll
    for (int r = 0; r < ROWS; ++r) {
        const int rid = r0 + r;
        const int b = rid >> 6;            // P == 64
        const float c = clockp[b];
        const float t = lpet[rid];
        const float rem = (t > c) ? (t - c) * (1.0f / 300.0f) : 0.0f;
        const int wi = lhw[rid];
        const int cs = lstage[rid] - 1;

        float2 sv = ((const float2*)(enc_col + ((size_t)b * S + cs) * D))[lane];
        float2 wv = make_float2(0.f, 0.f);
        if (wi >= 0)
            wv = ((const float2*)(enc_row + ((size_t)b * N + wi) * D))[lane];
        float2 dv = ((const float2*)W_dyn)[lane];   // row 0 of W_dyn; purge term is 0

        xs[r][0 * 64 + lane] = pack2(sv.x, sv.y);
        xs[r][1 * 64 + lane] = pack2(wv.x, wv.y);
        xs[r][2 * 64 + lane] = pack2(dv.x * rem, dv.y * rem);
    }
    __syncthreads();

    float acc0[ROWS], acc1[ROWS];
    #pragma unroll
    for (int r = 0; r < ROWS; ++r) { acc0[r] = 0.f; acc1[r] = 0.f; }

    for (int kc = 0; kc < K / 8; ++kc) {
        float w0[8], w1[8];
        #pragma unroll
        for (int kk = 0; kk < 8; ++kk) {
            w0[kk] = W_concat[(kc * 8 + kk) * D + lane];        // L2-resident
            w1[kk] = W_concat[(kc * 8 + kk) * D + lane + 64];
        }
        #pragma unroll
        for (int r = 0; r < ROWS; ++r) {
            const uint4 xq = *(const uint4*)&xs[r][kc * 4];     // 8 bf16 k-values (broadcast)
            float xv[8];
            xv[0] = blo(xq.x); xv[1] = bhi(xq.x);
            xv[2] = blo(xq.y); xv[3] = bhi(xq.y);
            xv[4] = blo(xq.z); xv[5] = bhi(xq.z);
            xv[6] = blo(xq.w); xv[7] = bhi(xq.w);
            #pragma unroll
            for (int kk = 0; kk < 8; ++kk) {
                acc0[r] = fmaf(xv[kk], w0[kk], acc0[r]);
                acc1[r] = fmaf(xv[kk], w1[kk], acc1[r]);
            }
        }
    }

    #pragma unroll
    for (int r = 0; r < ROWS; ++r) {
        const int rid = r0 + r;
        const int b = rid >> 6;
        const int p = rid & 63;
        const size_t o = ((size_t)b * (P + 2) + p) * D + lane;
        out[o] = acc0[r];
        out[o + 64] = acc1[r];
    }
}

// Kernel 2: arm embeddings -> out rows P, P+1. Reads pm_emb rows from `out`
// (written by kernel 1 earlier on the same stream).
__global__ __launch_bounds__(64) void arm_kernel(
    const float* __restrict__ enc_row,   // [B,N,D]
    const float* __restrict__ enc_col,   // [B,S,D]
    const float* __restrict__ W_robot,   // [K,D]
    const int* __restrict__ loc1, const int* __restrict__ loc2,
    const int* __restrict__ rec1, const int* __restrict__ rec2,
    const int* __restrict__ nst1, const int* __restrict__ nst2,
    float* __restrict__ out)             // [B,P+2,D]
{
    __shared__ uint32_t xs[K / 2];
    const int lane = threadIdx.x;
    const int b = blockIdx.x >> 1;
    const int arm = blockIdx.x & 1;
    const int loc = arm ? loc2[b] : loc1[b];
    const int rec = arm ? rec2[b] : rec1[b];
    int ns = arm ? nst2[b] : nst1[b];
    if (ns < 0) ns = 0;                      // where(next_stage>=0, ns, 0)

    // a_loc: loc_emb = [zeros, pm_emb(P rows), ones]
    float2 lv = make_float2(0.f, 0.f);
    if (loc >= 1 && loc <= P)
        lv = ((const float2*)(out + ((size_t)b * (P + 2) + (loc - 1)) * D))[lane];
    else if (loc == P + 1)
        lv = make_float2(1.f, 1.f);
    // a_wafer: rows_dummy gather (rec<0 -> zero row)
    float2 wv = make_float2(0.f, 0.f);
    if (rec >= 0)
        wv = ((const float2*)(enc_row + ((size_t)b * N + rec) * D))[lane];
    // a_ns: cols_pad = [zeros, enc_col, zeros]
    float2 nv = make_float2(0.f, 0.f);
    if (ns >= 1 && ns <= S)
        nv = ((const float2*)(enc_col + ((size_t)b * S + (ns - 1)) * D))[lane];

    xs[0 * 64 + lane] = pack2(lv.x, lv.y);
    xs[1 * 64 + lane] = pack2(wv.x, wv.y);
    xs[2 * 64 + lane] = pack2(nv.x, nv.y);
    __syncthreads();

    float acc0 = 0.f, acc1 = 0.f;
    for (int kc = 0; kc < K / 8; ++kc) {
        const uint4 xq = *(const uint4*)&xs[kc * 4];
        float xv[8];
        xv[0] = blo(xq.x); xv[1] = bhi(xq.x);
        xv[2] = blo(xq.y); xv[3] = bhi(xq.y);
        xv[4] = blo(xq.z); xv[5] = bhi(xq.z);
        xv[6] = blo(xq.w); xv[7] = bhi(xq.w);
        #pragma unroll
        for (int kk = 0; kk < 8; ++kk) {
            const float w0 = W_robot[(kc * 8 + kk) * D + lane];
            const float w1 = W_robot[(kc * 8 + kk) * D + lane + 64];
            acc0 = fmaf(xv[kk], w0, acc0);
            acc1 = fmaf(xv[kk], w1, acc1);
        }
    }
    const size_t o = ((size_t)b * (P + 2) + P + arm) * D + lane;
    out[o] = acc0;
    out[o + 64] = acc1;
}

extern "C" void kernel_launch(void* const* d_in, const int* in_sizes, int n_in,
                              void* d_out, int out_size, void* d_ws, size_t ws_size,
                              hipStream_t stream) {
    const float* enc_row  = (const float*)d_in[0];
    const float* enc_col  = (const float*)d_in[1];
    const float* clockp   = (const float*)d_in[2];
    const float* lpet     = (const float*)d_in[3];
    const float* W_dyn    = (const float*)d_in[4];
    const float* W_concat = (const float*)d_in[5];
    const float* W_robot  = (const float*)d_in[6];
    const int*   lhw      = (const int*)d_in[7];
    const int*   lstage   = (const int*)d_in[8];
    const int*   loc1     = (const int*)d_in[9];
    const int*   loc2     = (const int*)d_in[10];
    const int*   rec1     = (const int*)d_in[11];
    const int*   rec2     = (const int*)d_in[12];
    const int*   nst1     = (const int*)d_in[13];
    const int*   nst2     = (const int*)d_in[14];
    float* out = (float*)d_out;

    pm_emb_kernel<<<(B * P) / ROWS, 64, 0, stream>>>(
        enc_row, enc_col, clockp, lpet, W_dyn, W_concat, lhw, lstage, out);
    arm_kernel<<<2 * B, 64, 0, stream>>>(
        enc_row, enc_col, W_robot, loc1, loc2, rec1, rec2, nst1, nst2, out);
}

// Round 2
// 340.526 us; speedup vs baseline: 1.1247x; 1.1247x over previous
//
#include <hip/hip_runtime.h>
#include <stdint.h>

namespace {
constexpr int B = 128;
constexpr int N = 4096;
constexpr int S = 32;
constexpr int P = 64;
constexpr int D = 128;
constexpr int K = 384;          // 3*D
constexpr int KS = K / 32;      // 12 MFMA k-steps
constexpr int ROWPAD = 196;     // dwords per LDS activation row (192 used + 4 pad)
}

typedef __attribute__((ext_vector_type(8))) short short8;  // 8 bf16 (4 VGPRs)
typedef __attribute__((ext_vector_type(4))) float f32x4;   // MFMA C/D

// ---- bf16 pack helpers (RNE) ----
__device__ __forceinline__ uint32_t f2bf(float f) {
    union { float f; uint32_t u; } v; v.f = f;
    return (v.u + 0x7FFFu + ((v.u >> 16) & 1u)) >> 16;
}
__device__ __forceinline__ uint32_t pack2(float x, float y) {
    return f2bf(x) | (f2bf(y) << 16);
}
__device__ __forceinline__ float blo(uint32_t u) {
    union { uint32_t u; float f; } t; t.u = u << 16; return t.f;
}
__device__ __forceinline__ float bhi(uint32_t u) {
    union { uint32_t u; float f; } t; t.u = u & 0xFFFF0000u; return t.f;
}

// Prep: swizzle W_concat fp32[K,D] -> bf16 in B-fragment order:
// Wsw[ks][q][t][n][j]  (j contiguous, 8 bf16 = 16B per (ks,q,t,n))
// value = bf16(W[(ks*32 + q*8 + j)*D + t*16 + n])
__global__ __launch_bounds__(256) void prep_w_kernel(
    const float* __restrict__ W, uint32_t* __restrict__ Wsw)
{
    const int idx = blockIdx.x * 256 + threadIdx.x;   // 0..6143
    const int n  = idx & 15;
    const int t  = (idx >> 4) & 7;
    const int q  = (idx >> 7) & 3;
    const int ks = idx >> 9;
    const int col  = t * 16 + n;
    const int krow = ks * 32 + q * 8;
    uint32_t pk[4];
    #pragma unroll
    for (int jj = 0; jj < 4; ++jj) {
        const float a = W[(size_t)(krow + 2 * jj) * D + col];
        const float b = W[(size_t)(krow + 2 * jj + 1) * D + col];
        pk[jj] = pack2(a, b);
    }
    ((uint4*)Wsw)[idx] = make_uint4(pk[0], pk[1], pk[2], pk[3]);
}

// pm_emb GEMM via MFMA 16x16x32 bf16.
// Block = 256 threads (4 waves), computes 16 output rows x 128 cols.
// Wave w handles n-tiles t0=2w, t1=2w+1 for the same 16 rows.
// A (activations) staged bf16 in LDS row-major (pad to 196 dwords/row).
// B read directly from pre-swizzled global (L1/L2-resident, no barrier).
__global__ __launch_bounds__(256) void pm_gemm_kernel(
    const float* __restrict__ enc_row,   // [B,N,D]
    const float* __restrict__ enc_col,   // [B,S,D]
    const float* __restrict__ clockp,    // [B]
    const float* __restrict__ lpet,      // [B,P]
    const float* __restrict__ W_dyn,     // [2,D]
    const int*   __restrict__ lhw,       // [B,P]
    const int*   __restrict__ lstage,    // [B,P]
    const uint32_t* __restrict__ Wsw,    // swizzled bf16 W_concat
    float* __restrict__ out)             // [B,P+2,D]
{
    __shared__ uint32_t xs[16 * ROWPAD];           // 12.25 KB
    const int lane = threadIdx.x & 63;
    const int wave = threadIdx.x >> 6;
    const int r0 = blockIdx.x * 16;                // rid = b*P + p

    // ---- Phase 1: gather + build 16 activation rows (bf16 pairs) ----
    const float2 wd = ((const float2*)W_dyn)[lane];   // W_dyn row 0 (purge term = 0)
    #pragma unroll
    for (int rr = 0; rr < 4; ++rr) {
        const int r = wave * 4 + rr;
        const int rid = r0 + r;
        const int b = rid >> 6;                    // P == 64
        const float c = clockp[b];
        const float tt = lpet[rid];
        const float rem = (tt > c) ? (tt - c) * (1.0f / 300.0f) : 0.0f;
        const int wi = lhw[rid];
        const int cs = lstage[rid] - 1;

        const float2 sv = ((const float2*)(enc_col + ((size_t)b * S + cs) * D))[lane];
        float2 wv = make_float2(0.f, 0.f);
        if (wi >= 0)
            wv = ((const float2*)(enc_row + ((size_t)b * N + wi) * D))[lane];

        xs[r * ROWPAD + 0 * 64 + lane] = pack2(sv.x, sv.y);
        xs[r * ROWPAD + 1 * 64 + lane] = pack2(wv.x, wv.y);
        xs[r * ROWPAD + 2 * 64 + lane] = pack2(wd.x * rem, wd.y * rem);
    }
    __syncthreads();

    // ---- Phase 2: MFMA K-loop ----
    const int q = lane >> 4;        // quad
    const int n16 = lane & 15;      // A-row m / B-col n / C-col
    const int t0 = wave * 2, t1 = t0 + 1;

    f32x4 acc0 = {0.f, 0.f, 0.f, 0.f};
    f32x4 acc1 = {0.f, 0.f, 0.f, 0.f};
    const short8* wsw = (const short8*)Wsw;

    #pragma unroll
    for (int ks = 0; ks < KS; ++ks) {
        const short8 a = *(const short8*)(xs + n16 * ROWPAD + ks * 16 + q * 4);
        const short8 b0 = wsw[((ks * 4 + q) * 8 + t0) * 16 + n16];
        const short8 b1 = wsw[((ks * 4 + q) * 8 + t1) * 16 + n16];
        acc0 = __builtin_amdgcn_mfma_f32_16x16x32_bf16(a, b0, acc0, 0, 0, 0);
        acc1 = __builtin_amdgcn_mfma_f32_16x16x32_bf16(a, b1, acc1, 0, 0, 0);
    }

    // ---- Epilogue: C/D layout col=lane&15, row=(lane>>4)*4+reg ----
    #pragma unroll
    for (int i = 0; i < 4; ++i) {
        const int row = q * 4 + i;
        const int rid = r0 + row;
        const int bb = rid >> 6;
        const int pp = rid & 63;
        float* o = out + ((size_t)bb * (P + 2) + pp) * D;
        o[t0 * 16 + n16] = acc0[i];
        o[t1 * 16 + n16] = acc1[i];
    }
}

// Arm embeddings -> out rows P, P+1 (reads pm_emb rows from `out`).
__global__ __launch_bounds__(64) void arm_kernel(
    const float* __restrict__ enc_row,
    const float* __restrict__ enc_col,
    const float* __restrict__ W_robot,   // [K,D] fp32
    const int* __restrict__ loc1, const int* __restrict__ loc2,
    const int* __restrict__ rec1, const int* __restrict__ rec2,
    const int* __restrict__ nst1, const int* __restrict__ nst2,
    float* __restrict__ out)
{
    __shared__ uint32_t xs[K / 2];
    const int lane = threadIdx.x;
    const int b = blockIdx.x >> 1;
    const int arm = blockIdx.x & 1;
    const int loc = arm ? loc2[b] : loc1[b];
    const int rec = arm ? rec2[b] : rec1[b];
    int ns = arm ? nst2[b] : nst1[b];
    if (ns < 0) ns = 0;

    float2 lv = make_float2(0.f, 0.f);
    if (loc >= 1 && loc <= P)
        lv = ((const float2*)(out + ((size_t)b * (P + 2) + (loc - 1)) * D))[lane];
    else if (loc == P + 1)
        lv = make_float2(1.f, 1.f);
    float2 wv = make_float2(0.f, 0.f);
    if (rec >= 0)
        wv = ((const float2*)(enc_row + ((size_t)b * N + rec) * D))[lane];
    float2 nv = make_float2(0.f, 0.f);
    if (ns >= 1 && ns <= S)
        nv = ((const float2*)(enc_col + ((size_t)b * S + (ns - 1)) * D))[lane];

    xs[0 * 64 + lane] = pack2(lv.x, lv.y);
    xs[1 * 64 + lane] = pack2(wv.x, wv.y);
    xs[2 * 64 + lane] = pack2(nv.x, nv.y);
    __syncthreads();

    float acc0 = 0.f, acc1 = 0.f;
    for (int kc = 0; kc < K / 8; ++kc) {
        const uint4 xq = *(const uint4*)&xs[kc * 4];
        float xv[8];
        xv[0] = blo(xq.x); xv[1] = bhi(xq.x);
        xv[2] = blo(xq.y); xv[3] = bhi(xq.y);
        xv[4] = blo(xq.z); xv[5] = bhi(xq.z);
        xv[6] = blo(xq.w); xv[7] = bhi(xq.w);
        #pragma unroll
        for (int kk = 0; kk < 8; ++kk) {
            const float w0 = W_robot[(kc * 8 + kk) * D + lane];
            const float w1 = W_robot[(kc * 8 + kk) * D + lane + 64];
            acc0 = fmaf(xv[kk], w0, acc0);
            acc1 = fmaf(xv[kk], w1, acc1);
        }
    }
    const size_t o = ((size_t)b * (P + 2) + P + arm) * D + lane;
    out[o] = acc0;
    out[o + 64] = acc1;
}

extern "C" void kernel_launch(void* const* d_in, const int* in_sizes, int n_in,
                              void* d_out, int out_size, void* d_ws, size_t ws_size,
                              hipStream_t stream) {
    const float* enc_row  = (const float*)d_in[0];
    const float* enc_col  = (const float*)d_in[1];
    const float* clockp   = (const float*)d_in[2];
    const float* lpet     = (const float*)d_in[3];
    const float* W_dyn    = (const float*)d_in[4];
    const float* W_concat = (const float*)d_in[5];
    const float* W_robot  = (const float*)d_in[6];
    const int*   lhw      = (const int*)d_in[7];
    const int*   lstage   = (const int*)d_in[8];
    const int*   loc1     = (const int*)d_in[9];
    const int*   loc2     = (const int*)d_in[10];
    const int*   rec1     = (const int*)d_in[11];
    const int*   rec2     = (const int*)d_in[12];
    const int*   nst1     = (const int*)d_in[13];
    const int*   nst2     = (const int*)d_in[14];
    float* out = (float*)d_out;
    uint32_t* Wsw = (uint32_t*)d_ws;     // 96 KiB swizzled bf16 W_concat

    prep_w_kernel<<<24, 256, 0, stream>>>(W_concat, Wsw);
    pm_gemm_kernel<<<(B * P) / 16, 256, 0, stream>>>(
        enc_row, enc_col, clockp, lpet, W_dyn, lhw, lstage, Wsw, out);
    arm_kernel<<<2 * B, 64, 0, stream>>>(
        enc_row, enc_col, W_robot, loc1, loc2, rec1, rec2, nst1, nst2, out);
}

// Round 4
// 330.397 us; speedup vs baseline: 1.1592x; 1.0307x over previous
//
#include <hip/hip_runtime.h>
#include <stdint.h>

namespace {
constexpr int B = 128;
constexpr int N = 4096;
constexpr int S = 32;
constexpr int P = 64;
constexpr int D = 128;
constexpr int K = 384;          // 3*D
constexpr int KS = K / 32;      // 12 MFMA k-steps
constexpr int ROWPAD = 196;     // dwords per LDS activation row (192 used + 4 pad)
constexpr int PM_BLOCKS = (B * P) / 16;   // 512
constexpr int ARM_BLOCKS = (2 * B) / 16;  // 16
}

typedef __attribute__((ext_vector_type(8))) short short8;  // 8 bf16 (4 VGPRs)
typedef __attribute__((ext_vector_type(4))) float f32x4;   // MFMA C/D

// ---- bf16 pack helpers (RNE) ----
__device__ __forceinline__ uint32_t f2bf(float f) {
    union { float f; uint32_t u; } v; v.f = f;
    return (v.u + 0x7FFFu + ((v.u >> 16) & 1u)) >> 16;
}
__device__ __forceinline__ uint32_t pack2(float x, float y) {
    return f2bf(x) | (f2bf(y) << 16);
}

// Prep: swizzle W_concat and W_robot fp32[K,D] -> bf16 B-fragment order.
// Wsw[src][ks][q][t][n][j]: value = bf16(W[(ks*32+q*8+j)*D + t*16+n]).
// idx 0..6143 -> W_concat, 6144..12287 -> W_robot (contiguous in d_ws).
// NOTE: 6144 is NOT a power of two — must subtract, not mask (R3 bug).
__global__ __launch_bounds__(256) void prep_w_kernel(
    const float* __restrict__ Wc, const float* __restrict__ Wr,
    uint32_t* __restrict__ Wsw)
{
    const int idx = blockIdx.x * 256 + threadIdx.x;   // 0..12287
    const bool is_c = (idx < 6144);
    const float* W = is_c ? Wc : Wr;
    const int l = is_c ? idx : (idx - 6144);          // proper mod, 6144 != pow2
    const int n  = l & 15;
    const int t  = (l >> 4) & 7;
    const int q  = (l >> 7) & 3;
    const int ks = l >> 9;
    const int col  = t * 16 + n;
    const int krow = ks * 32 + q * 8;
    uint32_t pk[4];
    #pragma unroll
    for (int jj = 0; jj < 4; ++jj) {
        const float a = W[(size_t)(krow + 2 * jj) * D + col];
        const float b = W[(size_t)(krow + 2 * jj + 1) * D + col];
        pk[jj] = pack2(a, b);
    }
    ((uint4*)Wsw)[idx] = make_uint4(pk[0], pk[1], pk[2], pk[3]);
}

// Fused kernel. Blocks 0..511: pm_emb GEMM tiles (16 rows x 128 cols each).
// Blocks 512..527: arm embeddings, 16 (b,arm) instances per block, two-stage
// MFMA (stage1 recomputes the pm row each arm's loc points at -> no
// cross-block dependency; stage2 is the robot GEMM).
__global__ __launch_bounds__(256) void fused_kernel(
    const float* __restrict__ enc_row,   // [B,N,D]
    const float* __restrict__ enc_col,   // [B,S,D]
    const float* __restrict__ clockp,    // [B]
    const float* __restrict__ lpet,      // [B,P]
    const float* __restrict__ W_dyn,     // [2,D]
    const int*   __restrict__ lhw,       // [B,P]
    const int*   __restrict__ lstage,    // [B,P]
    const int* __restrict__ loc1, const int* __restrict__ loc2,
    const int* __restrict__ rec1, const int* __restrict__ rec2,
    const int* __restrict__ nst1, const int* __restrict__ nst2,
    const uint32_t* __restrict__ Wsw,    // swizzled bf16 W_concat ++ W_robot
    float* __restrict__ out)             // [B,P+2,D]
{
    __shared__ uint32_t xs[16 * ROWPAD];    // activations (pm) / stage1 (arm)
    __shared__ uint32_t xs2[16 * ROWPAD];   // arm stage2 activations
    __shared__ int locs[16];

    const int lane = threadIdx.x & 63;
    const int wave = threadIdx.x >> 6;
    const int q = lane >> 4;
    const int n16 = lane & 15;
    const int t0 = wave * 2, t1 = t0 + 1;
    const short8* wswc = (const short8*)Wsw;
    const short8* wswr = wswc + 6144;
    const float2 wd = ((const float2*)W_dyn)[lane];  // W_dyn row 0 (purge = 0)

    if (blockIdx.x < PM_BLOCKS) {
        // ================= pm path =================
        const int r0 = blockIdx.x * 16;              // rid = b*P + p
        #pragma unroll
        for (int rr = 0; rr < 4; ++rr) {
            const int r = wave * 4 + rr;
            const int rid = r0 + r;
            const int b = rid >> 6;                  // P == 64
            const float c = clockp[b];
            const float tt = lpet[rid];
            const float rem = (tt > c) ? (tt - c) * (1.0f / 300.0f) : 0.0f;
            const int wi = lhw[rid];
            const int cs = lstage[rid] - 1;
            const float2 sv = ((const float2*)(enc_col + ((size_t)b * S + cs) * D))[lane];
            float2 wv = make_float2(0.f, 0.f);
            if (wi >= 0)
                wv = ((const float2*)(enc_row + ((size_t)b * N + wi) * D))[lane];
            xs[r * ROWPAD + 0 * 64 + lane] = pack2(sv.x, sv.y);
            xs[r * ROWPAD + 1 * 64 + lane] = pack2(wv.x, wv.y);
            xs[r * ROWPAD + 2 * 64 + lane] = pack2(wd.x * rem, wd.y * rem);
        }
        __syncthreads();

        f32x4 acc0 = {0.f, 0.f, 0.f, 0.f};
        f32x4 acc1 = {0.f, 0.f, 0.f, 0.f};
        #pragma unroll
        for (int ks = 0; ks < KS; ++ks) {
            const short8 a = *(const short8*)(xs + n16 * ROWPAD + ks * 16 + q * 4);
            const short8 b0 = wswc[((ks * 4 + q) * 8 + t0) * 16 + n16];
            const short8 b1 = wswc[((ks * 4 + q) * 8 + t1) * 16 + n16];
            acc0 = __builtin_amdgcn_mfma_f32_16x16x32_bf16(a, b0, acc0, 0, 0, 0);
            acc1 = __builtin_amdgcn_mfma_f32_16x16x32_bf16(a, b1, acc1, 0, 0, 0);
        }
        #pragma unroll
        for (int i = 0; i < 4; ++i) {
            const int row = q * 4 + i;
            const int rid = r0 + row;
            const int bb = rid >> 6;
            const int pp = rid & 63;
            float* o = out + ((size_t)bb * (P + 2) + pp) * D;
            o[t0 * 16 + n16] = acc0[i];
            o[t1 * 16 + n16] = acc1[i];
        }
    } else {
        // ================= arm path =================
        const int ab = blockIdx.x - PM_BLOCKS;
        #pragma unroll
        for (int rr = 0; rr < 4; ++rr) {
            const int r = wave * 4 + rr;
            const int aid = ab * 16 + r;             // 0..255
            const int b = aid >> 1;
            const int arm = aid & 1;
            const int loc = arm ? loc2[b] : loc1[b];
            const int rec = arm ? rec2[b] : rec1[b];
            int ns = arm ? nst2[b] : nst1[b];
            if (ns < 0) ns = 0;
            if (lane == 0) locs[r] = loc;

            // stage-1 activation (recompute pm row loc-1) when loc in [1,P]
            if (loc >= 1 && loc <= P) {
                const int rid = b * P + (loc - 1);
                const float c = clockp[b];
                const float tt = lpet[rid];
                const float rem = (tt > c) ? (tt - c) * (1.0f / 300.0f) : 0.0f;
                const int wi = lhw[rid];
                const int cs = lstage[rid] - 1;
                const float2 sv = ((const float2*)(enc_col + ((size_t)b * S + cs) * D))[lane];
                float2 wv = make_float2(0.f, 0.f);
                if (wi >= 0)
                    wv = ((const float2*)(enc_row + ((size_t)b * N + wi) * D))[lane];
                xs[r * ROWPAD + 0 * 64 + lane] = pack2(sv.x, sv.y);
                xs[r * ROWPAD + 1 * 64 + lane] = pack2(wv.x, wv.y);
                xs[r * ROWPAD + 2 * 64 + lane] = pack2(wd.x * rem, wd.y * rem);
            } else {
                xs[r * ROWPAD + 0 * 64 + lane] = 0u;
                xs[r * ROWPAD + 1 * 64 + lane] = 0u;
                xs[r * ROWPAD + 2 * 64 + lane] = 0u;
            }

            // stage-2 gathered segments: a_wafer (cols 128..255), a_ns (256..383)
            float2 awv = make_float2(0.f, 0.f);
            if (rec >= 0)
                awv = ((const float2*)(enc_row + ((size_t)b * N + rec) * D))[lane];
            float2 anv = make_float2(0.f, 0.f);
            if (ns >= 1 && ns <= S)
                anv = ((const float2*)(enc_col + ((size_t)b * S + (ns - 1)) * D))[lane];
            xs2[r * ROWPAD + 1 * 64 + lane] = pack2(awv.x, awv.y);
            xs2[r * ROWPAD + 2 * 64 + lane] = pack2(anv.x, anv.y);
        }
        __syncthreads();

        // stage-1 MFMA: recompute pm rows (16 x 128)
        f32x4 acc0 = {0.f, 0.f, 0.f, 0.f};
        f32x4 acc1 = {0.f, 0.f, 0.f, 0.f};
        #pragma unroll
        for (int ks = 0; ks < KS; ++ks) {
            const short8 a = *(const short8*)(xs + n16 * ROWPAD + ks * 16 + q * 4);
            const short8 b0 = wswc[((ks * 4 + q) * 8 + t0) * 16 + n16];
            const short8 b1 = wswc[((ks * 4 + q) * 8 + t1) * 16 + n16];
            acc0 = __builtin_amdgcn_mfma_f32_16x16x32_bf16(a, b0, acc0, 0, 0, 0);
            acc1 = __builtin_amdgcn_mfma_f32_16x16x32_bf16(a, b1, acc1, 0, 0, 0);
        }

        // a_loc into stage-2 activation cols 0..127 (bf16), with loc==0 -> 0,
        // loc==P+1 -> 1.0 overrides
        unsigned short* u2 = (unsigned short*)xs2;
        #pragma unroll
        for (int i = 0; i < 4; ++i) {
            const int row = q * 4 + i;
            const int lc = locs[row];
            float v0 = acc0[i], v1 = acc1[i];
            if (lc == 0)      { v0 = 0.f; v1 = 0.f; }
            if (lc == P + 1)  { v0 = 1.f; v1 = 1.f; }
            u2[row * (2 * ROWPAD) + t0 * 16 + n16] = (unsigned short)f2bf(v0);
            u2[row * (2 * ROWPAD) + t1 * 16 + n16] = (unsigned short)f2bf(v1);
        }
        __syncthreads();

        // stage-2 MFMA: robot GEMM
        f32x4 racc0 = {0.f, 0.f, 0.f, 0.f};
        f32x4 racc1 = {0.f, 0.f, 0.f, 0.f};
        #pragma unroll
        for (int ks = 0; ks < KS; ++ks) {
            const short8 a = *(const short8*)(xs2 + n16 * ROWPAD + ks * 16 + q * 4);
            const short8 b0 = wswr[((ks * 4 + q) * 8 + t0) * 16 + n16];
            const short8 b1 = wswr[((ks * 4 + q) * 8 + t1) * 16 + n16];
            racc0 = __builtin_amdgcn_mfma_f32_16x16x32_bf16(a, b0, racc0, 0, 0, 0);
            racc1 = __builtin_amdgcn_mfma_f32_16x16x32_bf16(a, b1, racc1, 0, 0, 0);
        }
        #pragma unroll
        for (int i = 0; i < 4; ++i) {
            const int row = q * 4 + i;
            const int aid = ab * 16 + row;
            const int bb = aid >> 1;
            const int arm = aid & 1;
            float* o = out + ((size_t)bb * (P + 2) + P + arm) * D;
            o[t0 * 16 + n16] = racc0[i];
            o[t1 * 16 + n16] = racc1[i];
        }
    }
}

extern "C" void kernel_launch(void* const* d_in, const int* in_sizes, int n_in,
                              void* d_out, int out_size, void* d_ws, size_t ws_size,
                              hipStream_t stream) {
    const float* enc_row  = (const float*)d_in[0];
    const float* enc_col  = (const float*)d_in[1];
    const float* clockp   = (const float*)d_in[2];
    const float* lpet     = (const float*)d_in[3];
    const float* W_dyn    = (const float*)d_in[4];
    const float* W_concat = (const float*)d_in[5];
    const float* W_robot  = (const float*)d_in[6];
    const int*   lhw      = (const int*)d_in[7];
    const int*   lstage   = (const int*)d_in[8];
    const int*   loc1     = (const int*)d_in[9];
    const int*   loc2     = (const int*)d_in[10];
    const int*   rec1     = (const int*)d_in[11];
    const int*   rec2     = (const int*)d_in[12];
    const int*   nst1     = (const int*)d_in[13];
    const int*   nst2     = (const int*)d_in[14];
    float* out = (float*)d_out;
    uint32_t* Wsw = (uint32_t*)d_ws;     // 192 KiB: bf16 W_concat ++ W_robot, swizzled

    prep_w_kernel<<<48, 256, 0, stream>>>(W_concat, W_robot, Wsw);
    fused_kernel<<<PM_BLOCKS + ARM_BLOCKS, 256, 0, stream>>>(
        enc_row, enc_col, clockp, lpet, W_dyn, lhw, lstage,
        loc1, loc2, rec1, rec2, nst1, nst2, Wsw, out);
}